// Round 1
// baseline (653.695 us; speedup 1.0000x reference)
//
#include <hip/hip_runtime.h>

#define BLOCK 256
#define C 128
#define F4_PER_ROW (C / 4)   /* 32 float4 slots per row */
#define GRID_CAP 2048        /* 8 blocks/CU on 256 CUs; grid-stride the rest */

__global__ __launch_bounds__(BLOCK) void MultiCrossEntropyLoss_kernel(
    const float4* __restrict__ predicts4,
    const int*    __restrict__ labels,
    float*        __restrict__ out,
    int total4, float inv_n)
{
    const int tid    = blockIdx.x * BLOCK + threadIdx.x;
    const int stride = gridDim.x * BLOCK;           // multiple of 32 -> slot is loop-invariant
    const int slot   = tid & 31;                    // which float4 of its row this thread owns

    float s = 0.0f;
    // Fully-coalesced stream of the whole predicts array: lane i reads 16B at
    // base + i*16. The single thread whose slot holds labels[row] extracts the
    // element (branchless cndmask select; only ~2/64 lanes run the log).
    #pragma unroll 4
    for (int idx = tid; idx < total4; idx += stride) {
        const float4 v   = predicts4[idx];
        const int    lab = labels[idx >> 5];        // 32-way same-address -> 1 line/wave-iter, L2-hot
        if ((lab >> 2) == slot) {
            const float x01 = (lab & 1) ? v.y : v.x;
            const float x23 = (lab & 1) ? v.w : v.z;
            const float x   = (lab & 2) ? x23 : x01;
            s += __logf(x);
        }
    }

    // Wave (64-lane) shuffle reduction.
    #pragma unroll
    for (int off = 32; off > 0; off >>= 1)
        s += __shfl_down(s, off, 64);

    // Cross-wave reduction via LDS (BLOCK/64 = 4 waves).
    __shared__ float wave_sums[BLOCK / 64];
    const int lane = threadIdx.x & 63;
    const int wv   = threadIdx.x >> 6;
    if (lane == 0) wave_sums[wv] = s;
    __syncthreads();

    if (threadIdx.x == 0) {
        float bs = wave_sums[0] + wave_sums[1] + wave_sums[2] + wave_sums[3];
        // loss = -(1/N) * sum(log p); one atomic per block, pre-scaled.
        atomicAdd(out, -bs * inv_n);
    }
}

extern "C" void kernel_launch(void* const* d_in, const int* in_sizes, int n_in,
                              void* d_out, int out_size, void* d_ws, size_t ws_size,
                              hipStream_t stream) {
    const float* predicts = (const float*)d_in[0];
    const int*   labels   = (const int*)d_in[1];
    float*       out      = (float*)d_out;
    const int n = in_sizes[1];  // N = number of rows/labels

    // d_out is re-poisoned before every timed replay; we accumulate with
    // atomics, so zero it first (hipMemsetAsync is graph-capture-safe).
    hipMemsetAsync(d_out, 0, sizeof(float), stream);

    const int total4 = n * F4_PER_ROW;              // 32M float4 for N=1M
    int grid = (total4 + BLOCK - 1) / BLOCK;
    if (grid > GRID_CAP) grid = GRID_CAP;
    MultiCrossEntropyLoss_kernel<<<grid, BLOCK, 0, stream>>>(
        (const float4*)predicts, labels, out, total4, 1.0f / (float)n);
}